// Round 1
// baseline (906.961 us; speedup 1.0000x reference)
//
#include <hip/hip_runtime.h>

#define DIM 128

// ---------- degree / counts ----------
__global__ void deg_kernel(const int* __restrict__ dst, int* __restrict__ deg, int nE) {
    int e = blockIdx.x * blockDim.x + threadIdx.x;
    if (e < nE) atomicAdd(&deg[dst[e]], 1);
}

__global__ void cnt_kernel(const int* __restrict__ batch, int* __restrict__ cnt, int n) {
    int i = blockIdx.x * blockDim.x + threadIdx.x;
    if (i < n) atomicAdd(&cnt[batch[i]], 1);
}

__global__ void dinv_kernel(const int* __restrict__ deg, float* __restrict__ dinv, int n) {
    int i = blockIdx.x * blockDim.x + threadIdx.x;
    if (i < n) dinv[i] = rsqrtf((float)(deg[i] + 1));  // +1 self-loop
}

// ---------- GEMM: H[M,128] = X[M,128] @ W[128,128] ----------
// block = 128 threads (one col each), ROWS rows per block; X tile staged in LDS.
template <int ROWS>
__global__ void gemm_kernel(const float* __restrict__ X, const float* __restrict__ W,
                            float* __restrict__ H, int M) {
    __shared__ float xs[ROWS][DIM];
    const int c  = threadIdx.x;
    const int r0 = blockIdx.x * ROWS;
#pragma unroll
    for (int r = 0; r < ROWS; ++r) {
        int row = r0 + r;
        xs[r][c] = (row < M) ? X[(size_t)row * DIM + c] : 0.0f;
    }
    __syncthreads();
    float acc[ROWS];
#pragma unroll
    for (int r = 0; r < ROWS; ++r) acc[r] = 0.0f;
    for (int k = 0; k < DIM; ++k) {
        float w = W[k * DIM + c];
#pragma unroll
        for (int r = 0; r < ROWS; ++r) acc[r] += xs[r][k] * w;
    }
#pragma unroll
    for (int r = 0; r < ROWS; ++r) {
        int row = r0 + r;
        if (row < M) H[(size_t)row * DIM + c] = acc[r];
    }
}

// ---------- edge scatter: A[dst] += H[src] * dinv[src]*dinv[dst] ----------
// 128 threads per edge (wave-uniform edge id -> scalar loads of src/dst).
__global__ void scatter_kernel(const float* __restrict__ H, const int* __restrict__ src,
                               const int* __restrict__ dst, const float* __restrict__ dinv,
                               float* __restrict__ A, int nE) {
    int tid = blockIdx.x * blockDim.x + threadIdx.x;
    int e = tid >> 7;
    int d = tid & (DIM - 1);
    if (e >= nE) return;
    int s = src[e];
    int t = dst[e];
    float norm = dinv[s] * dinv[t];
    atomicAdd(&A[(size_t)t * DIM + d], H[(size_t)s * DIM + d] * norm);
}

// ---------- epilogue 1: A = relu(A + H*dinv^2 + b1) ----------
__global__ void epi1_kernel(float* __restrict__ A, const float* __restrict__ H,
                            const float* __restrict__ dinv, const float* __restrict__ b1,
                            int n) {
    int tid = blockIdx.x * blockDim.x + threadIdx.x;
    int i = tid >> 7;
    int d = tid & (DIM - 1);
    if (i >= n) return;
    float di = dinv[i];
    float v = A[tid] + H[tid] * di * di + b1[d];
    A[tid] = fmaxf(v, 0.0f);
}

// ---------- epilogue 2: A = A + H*dinv^2 (bias folded into finalize) ----------
__global__ void epi2_kernel(float* __restrict__ A, const float* __restrict__ H,
                            const float* __restrict__ dinv, int n) {
    int tid = blockIdx.x * blockDim.x + threadIdx.x;
    int i = tid >> 7;
    if (i >= n) return;
    float di = dinv[i];
    A[tid] = A[tid] + H[tid] * di * di;
}

// ---------- pooling: out[batch[i]] += A[i] ----------
__global__ void pool_kernel(const float* __restrict__ A, const int* __restrict__ batch,
                            float* __restrict__ out, int n) {
    int tid = blockIdx.x * blockDim.x + threadIdx.x;
    int i = tid >> 7;
    int d = tid & (DIM - 1);
    if (i >= n) return;
    atomicAdd(&out[(size_t)batch[i] * DIM + d], A[tid]);
}

// ---------- finalize: out = (sum + cnt*b2) / max(cnt,1) ----------
__global__ void fin_kernel(float* __restrict__ out, const int* __restrict__ cnt,
                           const float* __restrict__ b2, int nG) {
    int tid = blockIdx.x * blockDim.x + threadIdx.x;
    int g = tid >> 7;
    int d = tid & (DIM - 1);
    if (g >= nG) return;
    float c = (float)cnt[g];
    out[tid] = (out[tid] + c * b2[d]) / fmaxf(c, 1.0f);
}

extern "C" void kernel_launch(void* const* d_in, const int* in_sizes, int n_in,
                              void* d_out, int out_size, void* d_ws, size_t ws_size,
                              hipStream_t stream) {
    const float* x     = (const float*)d_in[0];
    const int*   ei    = (const int*)d_in[1];
    const int*   batch = (const int*)d_in[2];
    const float* W1    = (const float*)d_in[3];
    const float* b1    = (const float*)d_in[4];
    const float* W2    = (const float*)d_in[5];
    const float* b2    = (const float*)d_in[6];
    float* out = (float*)d_out;

    const int n  = in_sizes[0] / DIM;   // 50000 nodes
    const int nE = in_sizes[1] / 2;     // 800000 edges
    const int nG = out_size / DIM;      // 512 graphs

    const int* src = ei;
    const int* dst = ei + nE;

    const size_t nodeBytes = (size_t)n * DIM * sizeof(float);
    char* ws = (char*)d_ws;
    float* H    = (float*)ws;                           // [n,128]
    float* A    = (float*)(ws + nodeBytes);             // [n,128]
    int*   deg  = (int*)(ws + 2 * nodeBytes);           // [n]
    float* dinv = (float*)(ws + 2 * nodeBytes + (size_t)n * 4);  // [n]
    int*   cnt  = (int*)(ws + 2 * nodeBytes + (size_t)n * 8);    // [nG]

    const int B = 256;
    const int edgeThreads = nE * DIM;       // 102.4M, fits int
    const int nodeThreads = n * DIM;        // 6.4M

    // zero deg + dinv + cnt region
    hipMemsetAsync(deg, 0, (size_t)n * 8 + (size_t)nG * 4, stream);

    deg_kernel<<<(nE + B - 1) / B, B, 0, stream>>>(dst, deg, nE);
    cnt_kernel<<<(n + B - 1) / B, B, 0, stream>>>(batch, cnt, n);
    dinv_kernel<<<(n + B - 1) / B, B, 0, stream>>>(deg, dinv, n);

    // Layer 1
    gemm_kernel<8><<<(n + 7) / 8, DIM, 0, stream>>>(x, W1, H, n);
    hipMemsetAsync(A, 0, nodeBytes, stream);
    scatter_kernel<<<(edgeThreads + B - 1) / B, B, 0, stream>>>(H, src, dst, dinv, A, nE);
    epi1_kernel<<<(nodeThreads + B - 1) / B, B, 0, stream>>>(A, H, dinv, b1, n);

    // Layer 2
    gemm_kernel<8><<<(n + 7) / 8, DIM, 0, stream>>>(A, W2, H, n);
    hipMemsetAsync(A, 0, nodeBytes, stream);
    scatter_kernel<<<(edgeThreads + B - 1) / B, B, 0, stream>>>(H, src, dst, dinv, A, nE);
    epi2_kernel<<<(nodeThreads + B - 1) / B, B, 0, stream>>>(A, H, dinv, n);

    // Pool
    hipMemsetAsync(out, 0, (size_t)out_size * sizeof(float), stream);
    pool_kernel<<<(nodeThreads + B - 1) / B, B, 0, stream>>>(A, batch, out, n);
    fin_kernel<<<(nG * DIM + B - 1) / B, B, 0, stream>>>(out, cnt, b2, nG);
}

// Round 2
// 464.249 us; speedup vs baseline: 1.9536x; 1.9536x over previous
//
#include <hip/hip_runtime.h>

#define DIM 128

// ---------- histograms ----------
__global__ void deg_kernel(const int* __restrict__ dst, int* __restrict__ deg, int nE) {
    int e = blockIdx.x * blockDim.x + threadIdx.x;
    if (e < nE) atomicAdd(&deg[dst[e]], 1);
}

__global__ void cnt_kernel(const int* __restrict__ batch, int* __restrict__ cnt, int n) {
    int i = blockIdx.x * blockDim.x + threadIdx.x;
    if (i < n) atomicAdd(&cnt[batch[i]], 1);
}

__global__ void dinv_kernel(const int* __restrict__ deg, float* __restrict__ dinv, int n) {
    int i = blockIdx.x * blockDim.x + threadIdx.x;
    if (i < n) dinv[i] = rsqrtf((float)(deg[i] + 1));  // +1 self-loop
}

// ---------- exclusive scan of deg -> rowptr (+ cursor copy), single block ----------
__global__ void scan_kernel(const int* __restrict__ deg, int* __restrict__ rowptr,
                            int* __restrict__ cursor, int n) {
    __shared__ int sums[1024];
    const int t = threadIdx.x;
    const int C = (n + 1023) >> 10;
    int lo = t * C;
    int hi = lo + C; if (hi > n) hi = n; if (lo > n) lo = n;
    int s = 0;
    for (int i = lo; i < hi; ++i) s += deg[i];
    sums[t] = s;
    __syncthreads();
    for (int off = 1; off < 1024; off <<= 1) {
        int v = (t >= off) ? sums[t - off] : 0;
        __syncthreads();
        sums[t] += v;
        __syncthreads();
    }
    int run = (t == 0) ? 0 : sums[t - 1];
    for (int i = lo; i < hi; ++i) {
        rowptr[i] = run;
        cursor[i] = run;
        run += deg[i];
    }
    if (t == 1023) rowptr[n] = run;
}

// ---------- CSR fill: csr[pos(dst)] = src ----------
__global__ void fill_kernel(const int* __restrict__ src, const int* __restrict__ dst,
                            int* __restrict__ cursor, int* __restrict__ csr, int nE) {
    int e = blockIdx.x * blockDim.x + threadIdx.x;
    if (e >= nE) return;
    int pos = atomicAdd(&cursor[dst[e]], 1);
    csr[pos] = src[e];
}

// ---------- GEMM + row scale: Hs[r,c] = (X[r,:] @ W[:,c]) * dinv[r] ----------
template <int ROWS>
__global__ void gemm_kernel(const float* __restrict__ X, const float* __restrict__ W,
                            const float* __restrict__ dinv, float* __restrict__ Hs, int M) {
    __shared__ float xs[ROWS][DIM];
    const int c  = threadIdx.x;
    const int r0 = blockIdx.x * ROWS;
#pragma unroll
    for (int r = 0; r < ROWS; ++r) {
        int row = r0 + r;
        xs[r][c] = (row < M) ? X[(size_t)row * DIM + c] : 0.0f;
    }
    __syncthreads();
    float acc[ROWS];
#pragma unroll
    for (int r = 0; r < ROWS; ++r) acc[r] = 0.0f;
    for (int k = 0; k < DIM; ++k) {
        float w = W[k * DIM + c];
#pragma unroll
        for (int r = 0; r < ROWS; ++r) acc[r] += xs[r][k] * w;
    }
#pragma unroll
    for (int r = 0; r < ROWS; ++r) {
        int row = r0 + r;
        if (row < M) Hs[(size_t)row * DIM + c] = acc[r] * dinv[row];
    }
}

// ---------- gather layer 1: A[i] = relu(dinv[i]*(Hs[i] + sum_{s in N(i)} Hs[s]) + b1) ----------
__global__ void gather1_kernel(const float* __restrict__ Hs, const int* __restrict__ rowptr,
                               const int* __restrict__ csr, const float* __restrict__ dinv,
                               const float* __restrict__ b1, float* __restrict__ A, int n) {
    int i = blockIdx.x * 2 + (threadIdx.x >> 7);
    int d = threadIdx.x & (DIM - 1);
    if (i >= n) return;
    int e   = rowptr[i];
    int end = rowptr[i + 1];
    float acc = Hs[(size_t)i * DIM + d];  // self-loop (dinv[i] factored out)
    for (; e + 4 <= end; e += 4) {
        int s0 = csr[e], s1 = csr[e + 1], s2 = csr[e + 2], s3 = csr[e + 3];
        float v0 = Hs[(size_t)s0 * DIM + d];
        float v1 = Hs[(size_t)s1 * DIM + d];
        float v2 = Hs[(size_t)s2 * DIM + d];
        float v3 = Hs[(size_t)s3 * DIM + d];
        acc += (v0 + v1) + (v2 + v3);
    }
    for (; e < end; ++e) acc += Hs[(size_t)csr[e] * DIM + d];
    float v = dinv[i] * acc + b1[d];
    A[(size_t)i * DIM + d] = fmaxf(v, 0.0f);
}

// ---------- gather layer 2 + pool: out[batch[i]] += dinv[i]*(Hs[i] + sum Hs[nbr]) ----------
__global__ void gather2_kernel(const float* __restrict__ Hs, const int* __restrict__ rowptr,
                               const int* __restrict__ csr, const float* __restrict__ dinv,
                               const int* __restrict__ batch, float* __restrict__ out, int n) {
    int i = blockIdx.x * 2 + (threadIdx.x >> 7);
    int d = threadIdx.x & (DIM - 1);
    if (i >= n) return;
    int e   = rowptr[i];
    int end = rowptr[i + 1];
    float acc = Hs[(size_t)i * DIM + d];
    for (; e + 4 <= end; e += 4) {
        int s0 = csr[e], s1 = csr[e + 1], s2 = csr[e + 2], s3 = csr[e + 3];
        float v0 = Hs[(size_t)s0 * DIM + d];
        float v1 = Hs[(size_t)s1 * DIM + d];
        float v2 = Hs[(size_t)s2 * DIM + d];
        float v3 = Hs[(size_t)s3 * DIM + d];
        acc += (v0 + v1) + (v2 + v3);
    }
    for (; e < end; ++e) acc += Hs[(size_t)csr[e] * DIM + d];
    float v = dinv[i] * acc;  // b2 folded into fin
    atomicAdd(&out[(size_t)batch[i] * DIM + d], v);
}

// ---------- finalize: out = (sum + cnt*b2) / max(cnt,1) ----------
__global__ void fin_kernel(float* __restrict__ out, const int* __restrict__ cnt,
                           const float* __restrict__ b2, int nG) {
    int tid = blockIdx.x * blockDim.x + threadIdx.x;
    int g = tid >> 7;
    int d = tid & (DIM - 1);
    if (g >= nG) return;
    float c = (float)cnt[g];
    out[tid] = (out[tid] + c * b2[d]) / fmaxf(c, 1.0f);
}

extern "C" void kernel_launch(void* const* d_in, const int* in_sizes, int n_in,
                              void* d_out, int out_size, void* d_ws, size_t ws_size,
                              hipStream_t stream) {
    const float* x     = (const float*)d_in[0];
    const int*   ei    = (const int*)d_in[1];
    const int*   batch = (const int*)d_in[2];
    const float* W1    = (const float*)d_in[3];
    const float* b1    = (const float*)d_in[4];
    const float* W2    = (const float*)d_in[5];
    const float* b2    = (const float*)d_in[6];
    float* out = (float*)d_out;

    const int n  = in_sizes[0] / DIM;   // 50000
    const int nE = in_sizes[1] / 2;     // 800000
    const int nG = out_size / DIM;      // 512

    const int* src = ei;
    const int* dst = ei + nE;

    const size_t nodeBytes = (size_t)n * DIM * sizeof(float);
    char* ws = (char*)d_ws;
    size_t off = 0;
    float* Hs     = (float*)(ws + off); off += nodeBytes;          // 25.6 MB
    float* A      = (float*)(ws + off); off += nodeBytes;          // 25.6 MB
    int*   deg    = (int*)(ws + off);   off += (size_t)n * 4;
    float* dinv   = (float*)(ws + off); off += (size_t)n * 4;
    int*   cnt    = (int*)(ws + off);   off += (size_t)nG * 4;
    int*   rowptr = (int*)(ws + off);   off += (size_t)(n + 1) * 4;
    int*   cursor = (int*)(ws + off);   off += (size_t)n * 4;
    int*   csr    = (int*)(ws + off);   off += (size_t)nE * 4;     // 3.2 MB

    const int B = 256;
    const int nodeGrid = (n + 1) / 2;   // 2 nodes per 256-thread block

    // zero: deg, cnt (contiguous-ish: deg then dinv then cnt -> just zero deg & cnt separately)
    hipMemsetAsync(deg, 0, (size_t)n * 4, stream);
    hipMemsetAsync(cnt, 0, (size_t)nG * 4, stream);
    hipMemsetAsync(out, 0, (size_t)out_size * sizeof(float), stream);

    deg_kernel<<<(nE + B - 1) / B, B, 0, stream>>>(dst, deg, nE);
    cnt_kernel<<<(n + B - 1) / B, B, 0, stream>>>(batch, cnt, n);
    dinv_kernel<<<(n + B - 1) / B, B, 0, stream>>>(deg, dinv, n);
    scan_kernel<<<1, 1024, 0, stream>>>(deg, rowptr, cursor, n);
    fill_kernel<<<(nE + B - 1) / B, B, 0, stream>>>(src, dst, cursor, csr, nE);

    // Layer 1
    gemm_kernel<8><<<(n + 7) / 8, DIM, 0, stream>>>(x, W1, dinv, Hs, n);
    gather1_kernel<<<nodeGrid, 256, 0, stream>>>(Hs, rowptr, csr, dinv, b1, A, n);

    // Layer 2
    gemm_kernel<8><<<(n + 7) / 8, DIM, 0, stream>>>(A, W2, dinv, Hs, n);
    gather2_kernel<<<nodeGrid, 256, 0, stream>>>(Hs, rowptr, csr, dinv, batch, out, n);

    fin_kernel<<<(nG * DIM + B - 1) / B, B, 0, stream>>>(out, cnt, b2, nG);
}

// Round 3
// 362.044 us; speedup vs baseline: 2.5051x; 1.2823x over previous
//
#include <hip/hip_runtime.h>

#define DIM 128

// ---------- histograms ----------
__global__ void deg_kernel(const int* __restrict__ dst, int* __restrict__ deg, int nE) {
    int e = blockIdx.x * blockDim.x + threadIdx.x;
    if (e < nE) atomicAdd(&deg[dst[e]], 1);
}

__global__ void cnt_kernel(const int* __restrict__ batch, int* __restrict__ cnt, int n) {
    int i = blockIdx.x * blockDim.x + threadIdx.x;
    if (i < n) atomicAdd(&cnt[batch[i]], 1);
}

__global__ void dinv_kernel(const int* __restrict__ deg, float* __restrict__ dinv, int n) {
    int i = blockIdx.x * blockDim.x + threadIdx.x;
    if (i < n) dinv[i] = rsqrtf((float)(deg[i] + 1));  // +1 self-loop
}

// ---------- multi-block exclusive scan: deg -> rowptr/cursor ----------
__device__ inline int wave_incl_scan(int v) {
    int lane = threadIdx.x & 63;
#pragma unroll
    for (int off = 1; off < 64; off <<= 1) {
        int u = __shfl_up(v, off, 64);
        if (lane >= off) v += u;
    }
    return v;
}

// phase 1: per-block (1024 elems) sums
__global__ void scan1_kernel(const int* __restrict__ deg, int* __restrict__ bsum, int n) {
    __shared__ int wsum[16];
    int t = threadIdx.x;
    int i = blockIdx.x * 1024 + t;
    int v = (i < n) ? deg[i] : 0;
#pragma unroll
    for (int off = 32; off > 0; off >>= 1) v += __shfl_down(v, off, 64);
    if ((t & 63) == 0) wsum[t >> 6] = v;
    __syncthreads();
    if (t == 0) {
        int s = 0;
#pragma unroll
        for (int w = 0; w < 16; ++w) s += wsum[w];
        bsum[blockIdx.x] = s;
    }
}

// phase 2: one wave scans block sums (nb <= 64) exclusive in-place; writes total
__global__ void scan2_kernel(int* __restrict__ bsum, int* __restrict__ rowptr, int nb, int n) {
    int t = threadIdx.x;  // 64 threads
    int v = (t < nb) ? bsum[t] : 0;
    int incl = wave_incl_scan(v);
    if (t < nb) bsum[t] = incl - v;
    if (t == 63) rowptr[n] = incl;
}

// phase 3: block-local exclusive scan + block offset -> rowptr, cursor
__global__ void scan3_kernel(const int* __restrict__ deg, const int* __restrict__ bsum,
                             int* __restrict__ rowptr, int* __restrict__ cursor, int n) {
    __shared__ int wsum[16];
    int t = threadIdx.x;
    int i = blockIdx.x * 1024 + t;
    int v = (i < n) ? deg[i] : 0;
    int incl = wave_incl_scan(v);
    int wid = t >> 6;
    if ((t & 63) == 63) wsum[wid] = incl;
    __syncthreads();
    if (t == 0) {
        int run = 0;
#pragma unroll
        for (int w = 0; w < 16; ++w) { int x = wsum[w]; wsum[w] = run; run += x; }
    }
    __syncthreads();
    if (i < n) {
        int excl = incl - v + wsum[wid] + bsum[blockIdx.x];
        rowptr[i] = excl;
        cursor[i] = excl;
    }
}

// ---------- CSR fill: csr[pos(dst)] = src ----------
__global__ void fill_kernel(const int* __restrict__ src, const int* __restrict__ dst,
                            int* __restrict__ cursor, int* __restrict__ csr, int nE) {
    int e = blockIdx.x * blockDim.x + threadIdx.x;
    if (e >= nE) return;
    int pos = atomicAdd(&cursor[dst[e]], 1);
    csr[pos] = src[e];
}

// ---------- GEMM + row scale: Hs[r,c] = (X[r,:] @ W[:,c]) * dinv[r] ----------
template <int ROWS>
__global__ void gemm_kernel(const float* __restrict__ X, const float* __restrict__ W,
                            const float* __restrict__ dinv, float* __restrict__ Hs, int M) {
    __shared__ float xs[ROWS][DIM];
    const int c  = threadIdx.x;
    const int r0 = blockIdx.x * ROWS;
#pragma unroll
    for (int r = 0; r < ROWS; ++r) {
        int row = r0 + r;
        xs[r][c] = (row < M) ? X[(size_t)row * DIM + c] : 0.0f;
    }
    __syncthreads();
    float acc[ROWS];
#pragma unroll
    for (int r = 0; r < ROWS; ++r) acc[r] = 0.0f;
    for (int k = 0; k < DIM; ++k) {
        float w = W[k * DIM + c];
#pragma unroll
        for (int r = 0; r < ROWS; ++r) acc[r] += xs[r][k] * w;
    }
#pragma unroll
    for (int r = 0; r < ROWS; ++r) {
        int row = r0 + r;
        if (row < M) Hs[(size_t)row * DIM + c] = acc[r] * dinv[row];
    }
}

// ---------- gather layer 1: A[i] = relu(dinv[i]*(Hs[i] + sum_{s in N(i)} Hs[s]) + b1) ----------
__global__ void gather1_kernel(const float* __restrict__ Hs, const int* __restrict__ rowptr,
                               const int* __restrict__ csr, const float* __restrict__ dinv,
                               const float* __restrict__ b1, float* __restrict__ A, int n) {
    int i = blockIdx.x * 2 + (threadIdx.x >> 7);
    int d = threadIdx.x & (DIM - 1);
    if (i >= n) return;
    int e   = rowptr[i];
    int end = rowptr[i + 1];
    float acc = Hs[(size_t)i * DIM + d];  // self-loop (dinv[i] factored out)
    for (; e + 4 <= end; e += 4) {
        int s0 = csr[e], s1 = csr[e + 1], s2 = csr[e + 2], s3 = csr[e + 3];
        float v0 = Hs[(size_t)s0 * DIM + d];
        float v1 = Hs[(size_t)s1 * DIM + d];
        float v2 = Hs[(size_t)s2 * DIM + d];
        float v3 = Hs[(size_t)s3 * DIM + d];
        acc += (v0 + v1) + (v2 + v3);
    }
    for (; e < end; ++e) acc += Hs[(size_t)csr[e] * DIM + d];
    float v = dinv[i] * acc + b1[d];
    A[(size_t)i * DIM + d] = fmaxf(v, 0.0f);
}

// ---------- gather layer 2 + pool: out[batch[i]] += dinv[i]*(Hs[i] + sum Hs[nbr]) ----------
__global__ void gather2_kernel(const float* __restrict__ Hs, const int* __restrict__ rowptr,
                               const int* __restrict__ csr, const float* __restrict__ dinv,
                               const int* __restrict__ batch, float* __restrict__ out, int n) {
    int i = blockIdx.x * 2 + (threadIdx.x >> 7);
    int d = threadIdx.x & (DIM - 1);
    if (i >= n) return;
    int e   = rowptr[i];
    int end = rowptr[i + 1];
    float acc = Hs[(size_t)i * DIM + d];
    for (; e + 4 <= end; e += 4) {
        int s0 = csr[e], s1 = csr[e + 1], s2 = csr[e + 2], s3 = csr[e + 3];
        float v0 = Hs[(size_t)s0 * DIM + d];
        float v1 = Hs[(size_t)s1 * DIM + d];
        float v2 = Hs[(size_t)s2 * DIM + d];
        float v3 = Hs[(size_t)s3 * DIM + d];
        acc += (v0 + v1) + (v2 + v3);
    }
    for (; e < end; ++e) acc += Hs[(size_t)csr[e] * DIM + d];
    float v = dinv[i] * acc;  // b2 folded into fin
    atomicAdd(&out[(size_t)batch[i] * DIM + d], v);
}

// ---------- finalize: out = (sum + cnt*b2) / max(cnt,1) ----------
__global__ void fin_kernel(float* __restrict__ out, const int* __restrict__ cnt,
                           const float* __restrict__ b2, int nG) {
    int tid = blockIdx.x * blockDim.x + threadIdx.x;
    int g = tid >> 7;
    int d = tid & (DIM - 1);
    if (g >= nG) return;
    float c = (float)cnt[g];
    out[tid] = (out[tid] + c * b2[d]) / fmaxf(c, 1.0f);
}

extern "C" void kernel_launch(void* const* d_in, const int* in_sizes, int n_in,
                              void* d_out, int out_size, void* d_ws, size_t ws_size,
                              hipStream_t stream) {
    const float* x     = (const float*)d_in[0];
    const int*   ei    = (const int*)d_in[1];
    const int*   batch = (const int*)d_in[2];
    const float* W1    = (const float*)d_in[3];
    const float* b1    = (const float*)d_in[4];
    const float* W2    = (const float*)d_in[5];
    const float* b2    = (const float*)d_in[6];
    float* out = (float*)d_out;

    const int n  = in_sizes[0] / DIM;   // 50000
    const int nE = in_sizes[1] / 2;     // 800000
    const int nG = out_size / DIM;      // 512

    const int* src = ei;
    const int* dst = ei + nE;

    const size_t nodeBytes = (size_t)n * DIM * sizeof(float);
    char* ws = (char*)d_ws;
    size_t off = 0;
    float* Hs     = (float*)(ws + off); off += nodeBytes;          // 25.6 MB
    float* A      = (float*)(ws + off); off += nodeBytes;          // 25.6 MB
    int*   deg    = (int*)(ws + off);   off += (size_t)n * 4;
    float* dinv   = (float*)(ws + off); off += (size_t)n * 4;
    int*   cnt    = (int*)(ws + off);   off += (size_t)nG * 4;
    int*   rowptr = (int*)(ws + off);   off += (size_t)(n + 1) * 4;
    int*   cursor = (int*)(ws + off);   off += (size_t)n * 4;
    int*   bsum   = (int*)(ws + off);   off += 256;
    int*   csr    = (int*)(ws + off);   off += (size_t)nE * 4;     // 3.2 MB

    const int B = 256;
    const int nb = (n + 1023) / 1024;   // 49 (must be <= 64)
    const int nodeGrid = (n + 1) / 2;   // 2 nodes per 256-thread block

    hipMemsetAsync(deg, 0, (size_t)n * 4, stream);
    hipMemsetAsync(cnt, 0, (size_t)nG * 4, stream);
    hipMemsetAsync(out, 0, (size_t)out_size * sizeof(float), stream);

    deg_kernel<<<(nE + B - 1) / B, B, 0, stream>>>(dst, deg, nE);
    cnt_kernel<<<(n + B - 1) / B, B, 0, stream>>>(batch, cnt, n);
    dinv_kernel<<<(n + B - 1) / B, B, 0, stream>>>(deg, dinv, n);
    scan1_kernel<<<nb, 1024, 0, stream>>>(deg, bsum, n);
    scan2_kernel<<<1, 64, 0, stream>>>(bsum, rowptr, nb, n);
    scan3_kernel<<<nb, 1024, 0, stream>>>(deg, bsum, rowptr, cursor, n);
    fill_kernel<<<(nE + B - 1) / B, B, 0, stream>>>(src, dst, cursor, csr, nE);

    // Layer 1
    gemm_kernel<8><<<(n + 7) / 8, DIM, 0, stream>>>(x, W1, dinv, Hs, n);
    gather1_kernel<<<nodeGrid, 256, 0, stream>>>(Hs, rowptr, csr, dinv, b1, A, n);

    // Layer 2
    gemm_kernel<8><<<(n + 7) / 8, DIM, 0, stream>>>(A, W2, dinv, Hs, n);
    gather2_kernel<<<nodeGrid, 256, 0, stream>>>(Hs, rowptr, csr, dinv, batch, out, n);

    fin_kernel<<<(nG * DIM + B - 1) / B, B, 0, stream>>>(out, cnt, b2, nG);
}

// Round 4
// 322.909 us; speedup vs baseline: 2.8087x; 1.1212x over previous
//
#include <hip/hip_runtime.h>

typedef unsigned int uint;
#define DIM 128

// ---------- bf16 pack/unpack helpers ----------
__device__ inline float bflo(uint u) { return __uint_as_float(u << 16); }
__device__ inline float bfhi(uint u) { return __uint_as_float(u & 0xffff0000u); }
__device__ inline uint packbf2(float a, float b) {
    uint ua = __float_as_uint(a), ub = __float_as_uint(b);
    ua = (ua + 0x7fffu + ((ua >> 16) & 1u)) >> 16;
    ub = (ub + 0x7fffu + ((ub >> 16) & 1u)) & 0xffff0000u;
    return ua | ub;
}

// ---------- histograms ----------
__global__ void deg_kernel(const int* __restrict__ dst, int* __restrict__ deg, int nE) {
    int e = blockIdx.x * blockDim.x + threadIdx.x;
    if (e < nE) atomicAdd(&deg[dst[e]], 1);
}

__global__ void cnt_kernel(const int* __restrict__ batch, int* __restrict__ cnt, int n) {
    int i = blockIdx.x * blockDim.x + threadIdx.x;
    if (i < n) atomicAdd(&cnt[batch[i]], 1);
}

__global__ void dinv_kernel(const int* __restrict__ deg, float* __restrict__ dinv, int n) {
    int i = blockIdx.x * blockDim.x + threadIdx.x;
    if (i < n) dinv[i] = rsqrtf((float)(deg[i] + 1));  // +1 self-loop
}

// ---------- multi-block exclusive scan: deg -> rowptr/cursor ----------
__device__ inline int wave_incl_scan(int v) {
    int lane = threadIdx.x & 63;
#pragma unroll
    for (int off = 1; off < 64; off <<= 1) {
        int u = __shfl_up(v, off, 64);
        if (lane >= off) v += u;
    }
    return v;
}

__global__ void scan1_kernel(const int* __restrict__ deg, int* __restrict__ bsum, int n) {
    __shared__ int wsum[16];
    int t = threadIdx.x;
    int i = blockIdx.x * 1024 + t;
    int v = (i < n) ? deg[i] : 0;
#pragma unroll
    for (int off = 32; off > 0; off >>= 1) v += __shfl_down(v, off, 64);
    if ((t & 63) == 0) wsum[t >> 6] = v;
    __syncthreads();
    if (t == 0) {
        int s = 0;
#pragma unroll
        for (int w = 0; w < 16; ++w) s += wsum[w];
        bsum[blockIdx.x] = s;
    }
}

__global__ void scan2_kernel(int* __restrict__ bsum, int* __restrict__ rowptr, int nb, int n) {
    int t = threadIdx.x;  // 64 threads
    int v = (t < nb) ? bsum[t] : 0;
    int incl = wave_incl_scan(v);
    if (t < nb) bsum[t] = incl - v;
    if (t == 63) rowptr[n] = incl;
}

__global__ void scan3_kernel(const int* __restrict__ deg, const int* __restrict__ bsum,
                             int* __restrict__ rowptr, int* __restrict__ cursor, int n) {
    __shared__ int wsum[16];
    int t = threadIdx.x;
    int i = blockIdx.x * 1024 + t;
    int v = (i < n) ? deg[i] : 0;
    int incl = wave_incl_scan(v);
    int wid = t >> 6;
    if ((t & 63) == 63) wsum[wid] = incl;
    __syncthreads();
    if (t == 0) {
        int run = 0;
#pragma unroll
        for (int w = 0; w < 16; ++w) { int x = wsum[w]; wsum[w] = run; run += x; }
    }
    __syncthreads();
    if (i < n) {
        int excl = incl - v + wsum[wid] + bsum[blockIdx.x];
        rowptr[i] = excl;
        cursor[i] = excl;
    }
}

// ---------- CSR fill ----------
__global__ void fill_kernel(const int* __restrict__ src, const int* __restrict__ dst,
                            int* __restrict__ cursor, int* __restrict__ csr, int nE) {
    int e = blockIdx.x * blockDim.x + threadIdx.x;
    if (e >= nE) return;
    int pos = atomicAdd(&cursor[dst[e]], 1);
    csr[pos] = src[e];
}

// ---------- GEMM: Hs[r] = bf16( (X[r,:] @ W) * dinv[r] ), packed pairs ----------
// 64-thread blocks; lane t owns columns (2t, 2t+1); ROWS rows per block.
template <int ROWS, bool BF16IN>
__global__ __launch_bounds__(64) void gemm_kernel(const void* __restrict__ Xv,
                                                  const float* __restrict__ W,
                                                  const float* __restrict__ dinv,
                                                  uint* __restrict__ Hs, int M) {
    __shared__ float xs[ROWS][DIM];
    const int t = threadIdx.x;
    const int r0 = blockIdx.x * ROWS;
#pragma unroll
    for (int r = 0; r < ROWS; ++r) {
        int row = r0 + r;
        if (row < M) {
            if (BF16IN) {
                uint u = ((const uint*)Xv)[(size_t)row * 64 + t];
                xs[r][2 * t] = bflo(u); xs[r][2 * t + 1] = bfhi(u);
            } else {
                float2 v = ((const float2*)Xv)[(size_t)row * 64 + t];
                xs[r][2 * t] = v.x; xs[r][2 * t + 1] = v.y;
            }
        } else {
            xs[r][2 * t] = 0.0f; xs[r][2 * t + 1] = 0.0f;
        }
    }
    __syncthreads();
    float2 acc[ROWS];
#pragma unroll
    for (int r = 0; r < ROWS; ++r) acc[r] = make_float2(0.0f, 0.0f);
    const float2* Wp = (const float2*)W;
    float2 w[4];
#pragma unroll
    for (int j = 0; j < 4; ++j) w[j] = Wp[j * 64 + t];
    for (int k4 = 0; k4 < DIM; k4 += 4) {
        float2 wn[4];
        if (k4 + 4 < DIM) {
#pragma unroll
            for (int j = 0; j < 4; ++j) wn[j] = Wp[(k4 + 4 + j) * 64 + t];
        }
#pragma unroll
        for (int r = 0; r < ROWS; ++r) {
            float4 xv = *(const float4*)&xs[r][k4];
            acc[r].x += xv.x * w[0].x; acc[r].y += xv.x * w[0].y;
            acc[r].x += xv.y * w[1].x; acc[r].y += xv.y * w[1].y;
            acc[r].x += xv.z * w[2].x; acc[r].y += xv.z * w[2].y;
            acc[r].x += xv.w * w[3].x; acc[r].y += xv.w * w[3].y;
        }
        if (k4 + 4 < DIM) {
#pragma unroll
            for (int j = 0; j < 4; ++j) w[j] = wn[j];
        }
    }
#pragma unroll
    for (int r = 0; r < ROWS; ++r) {
        int row = r0 + r;
        if (row < M) {
            float di = dinv[row];
            Hs[(size_t)row * 64 + t] = packbf2(acc[r].x * di, acc[r].y * di);
        }
    }
}

// ---------- gather layer 1: A[i] = bf16(relu(dinv[i]*(Hs[i]+sum Hs[nbr]) + b1)) ----------
// one wave per node; lane t owns columns (2t, 2t+1) packed in one uint.
__global__ __launch_bounds__(256) void gather1_kernel(const uint* __restrict__ Hs,
        const int* __restrict__ rowptr, const int* __restrict__ csr,
        const float* __restrict__ dinv, const float* __restrict__ b1,
        uint* __restrict__ A, int n) {
    int i = blockIdx.x * 4 + (threadIdx.x >> 6);
    int t = threadIdx.x & 63;
    if (i >= n) return;
    int e = rowptr[i], end = rowptr[i + 1];
    uint u = Hs[(size_t)i * 64 + t];  // self-loop
    float ax = bflo(u), ay = bfhi(u);
    for (; e + 4 <= end; e += 4) {
        int s0 = csr[e], s1 = csr[e + 1], s2 = csr[e + 2], s3 = csr[e + 3];
        uint u0 = Hs[(size_t)s0 * 64 + t];
        uint u1 = Hs[(size_t)s1 * 64 + t];
        uint u2 = Hs[(size_t)s2 * 64 + t];
        uint u3 = Hs[(size_t)s3 * 64 + t];
        ax += (bflo(u0) + bflo(u1)) + (bflo(u2) + bflo(u3));
        ay += (bfhi(u0) + bfhi(u1)) + (bfhi(u2) + bfhi(u3));
    }
    for (; e < end; ++e) {
        uint uu = Hs[(size_t)csr[e] * 64 + t];
        ax += bflo(uu); ay += bfhi(uu);
    }
    float di = dinv[i];
    float2 b = *(const float2*)(b1 + 2 * t);
    A[(size_t)i * 64 + t] = packbf2(fmaxf(di * ax + b.x, 0.0f),
                                    fmaxf(di * ay + b.y, 0.0f));
}

// ---------- gather layer 2 + pool ----------
__global__ __launch_bounds__(256) void gather2_kernel(const uint* __restrict__ Hs,
        const int* __restrict__ rowptr, const int* __restrict__ csr,
        const float* __restrict__ dinv, const int* __restrict__ batch,
        float* __restrict__ out, int n) {
    int i = blockIdx.x * 4 + (threadIdx.x >> 6);
    int t = threadIdx.x & 63;
    if (i >= n) return;
    int e = rowptr[i], end = rowptr[i + 1];
    uint u = Hs[(size_t)i * 64 + t];
    float ax = bflo(u), ay = bfhi(u);
    for (; e + 4 <= end; e += 4) {
        int s0 = csr[e], s1 = csr[e + 1], s2 = csr[e + 2], s3 = csr[e + 3];
        uint u0 = Hs[(size_t)s0 * 64 + t];
        uint u1 = Hs[(size_t)s1 * 64 + t];
        uint u2 = Hs[(size_t)s2 * 64 + t];
        uint u3 = Hs[(size_t)s3 * 64 + t];
        ax += (bflo(u0) + bflo(u1)) + (bflo(u2) + bflo(u3));
        ay += (bfhi(u0) + bfhi(u1)) + (bfhi(u2) + bfhi(u3));
    }
    for (; e < end; ++e) {
        uint uu = Hs[(size_t)csr[e] * 64 + t];
        ax += bflo(uu); ay += bfhi(uu);
    }
    float di = dinv[i];
    float* o = out + (size_t)batch[i] * DIM + 2 * t;
    atomicAdd(o, di * ax);
    atomicAdd(o + 1, di * ay);
}

// ---------- finalize ----------
__global__ void fin_kernel(float* __restrict__ out, const int* __restrict__ cnt,
                           const float* __restrict__ b2, int nG) {
    int tid = blockIdx.x * blockDim.x + threadIdx.x;
    int g = tid >> 7;
    int d = tid & (DIM - 1);
    if (g >= nG) return;
    float c = (float)cnt[g];
    out[tid] = (out[tid] + c * b2[d]) / fmaxf(c, 1.0f);
}

extern "C" void kernel_launch(void* const* d_in, const int* in_sizes, int n_in,
                              void* d_out, int out_size, void* d_ws, size_t ws_size,
                              hipStream_t stream) {
    const float* x     = (const float*)d_in[0];
    const int*   ei    = (const int*)d_in[1];
    const int*   batch = (const int*)d_in[2];
    const float* W1    = (const float*)d_in[3];
    const float* b1    = (const float*)d_in[4];
    const float* W2    = (const float*)d_in[5];
    const float* b2    = (const float*)d_in[6];
    float* out = (float*)d_out;

    const int n  = in_sizes[0] / DIM;   // 50000
    const int nE = in_sizes[1] / 2;     // 800000
    const int nG = out_size / DIM;      // 512

    const int* src = ei;
    const int* dst = ei + nE;

    const size_t packBytes = (size_t)n * 64 * sizeof(uint);  // 12.8 MB
    char* ws = (char*)d_ws;
    size_t off = 0;
    uint*  Hs     = (uint*)(ws + off); off += packBytes;
    uint*  A      = (uint*)(ws + off); off += packBytes;
    int*   deg    = (int*)(ws + off);  off += (size_t)n * 4;
    float* dinv   = (float*)(ws + off); off += (size_t)n * 4;
    int*   cnt    = (int*)(ws + off);  off += (size_t)nG * 4;
    int*   rowptr = (int*)(ws + off);  off += (size_t)(n + 1) * 4;
    int*   cursor = (int*)(ws + off);  off += (size_t)n * 4;
    int*   bsum   = (int*)(ws + off);  off += 256;
    int*   csr    = (int*)(ws + off);  off += (size_t)nE * 4;

    const int B = 256;
    const int nb = (n + 1023) / 1024;        // 49 (<= 64)
    const int ROWS = 16;
    const int gemmGrid = (n + ROWS - 1) / ROWS;
    const int gatherGrid = (n + 3) / 4;

    hipMemsetAsync(deg, 0, (size_t)n * 4, stream);
    hipMemsetAsync(cnt, 0, (size_t)nG * 4, stream);
    hipMemsetAsync(out, 0, (size_t)out_size * sizeof(float), stream);

    deg_kernel<<<(nE + B - 1) / B, B, 0, stream>>>(dst, deg, nE);
    cnt_kernel<<<(n + B - 1) / B, B, 0, stream>>>(batch, cnt, n);
    dinv_kernel<<<(n + B - 1) / B, B, 0, stream>>>(deg, dinv, n);
    scan1_kernel<<<nb, 1024, 0, stream>>>(deg, bsum, n);
    scan2_kernel<<<1, 64, 0, stream>>>(bsum, rowptr, nb, n);
    scan3_kernel<<<nb, 1024, 0, stream>>>(deg, bsum, rowptr, cursor, n);
    fill_kernel<<<(nE + B - 1) / B, B, 0, stream>>>(src, dst, cursor, csr, nE);

    // Layer 1
    gemm_kernel<16, false><<<gemmGrid, 64, 0, stream>>>(x, W1, dinv, Hs, n);
    gather1_kernel<<<gatherGrid, 256, 0, stream>>>(Hs, rowptr, csr, dinv, b1, A, n);

    // Layer 2
    gemm_kernel<16, true><<<gemmGrid, 64, 0, stream>>>(A, W2, dinv, Hs, n);
    gather2_kernel<<<gatherGrid, 256, 0, stream>>>(Hs, rowptr, csr, dinv, batch, out, n);

    fin_kernel<<<(nG * DIM + B - 1) / B, B, 0, stream>>>(out, cnt, b2, nG);
}

// Round 5
// 286.289 us; speedup vs baseline: 3.1680x; 1.1279x over previous
//
#include <hip/hip_runtime.h>

typedef unsigned int uint;
#define DIM 128

// ---------- bf16 pack/unpack helpers ----------
__device__ inline float bflo(uint u) { return __uint_as_float(u << 16); }
__device__ inline float bfhi(uint u) { return __uint_as_float(u & 0xffff0000u); }
__device__ inline uint packbf2(float a, float b) {
    uint ua = __float_as_uint(a), ub = __float_as_uint(b);
    ua = (ua + 0x7fffu + ((ua >> 16) & 1u)) >> 16;
    ub = (ub + 0x7fffu + ((ub >> 16) & 1u)) & 0xffff0000u;
    return ua | ub;
}

// ---------- fused histograms: deg over dst, cnt over batch ----------
__global__ void degcnt_kernel(const int* __restrict__ dst, int* __restrict__ deg, int nE,
                              const int* __restrict__ batch, int* __restrict__ cnt, int n) {
    int i = blockIdx.x * blockDim.x + threadIdx.x;
    if (i < nE) atomicAdd(&deg[dst[i]], 1);
    if (i < n)  atomicAdd(&cnt[batch[i]], 1);
}

// ---------- multi-block exclusive scan: deg -> rowptr/cursor (+ dinv) ----------
__device__ inline int wave_incl_scan(int v) {
    int lane = threadIdx.x & 63;
#pragma unroll
    for (int off = 1; off < 64; off <<= 1) {
        int u = __shfl_up(v, off, 64);
        if (lane >= off) v += u;
    }
    return v;
}

__global__ void scan1_kernel(const int* __restrict__ deg, int* __restrict__ bsum, int n) {
    __shared__ int wsum[16];
    int t = threadIdx.x;
    int i = blockIdx.x * 1024 + t;
    int v = (i < n) ? deg[i] : 0;
#pragma unroll
    for (int off = 32; off > 0; off >>= 1) v += __shfl_down(v, off, 64);
    if ((t & 63) == 0) wsum[t >> 6] = v;
    __syncthreads();
    if (t == 0) {
        int s = 0;
#pragma unroll
        for (int w = 0; w < 16; ++w) s += wsum[w];
        bsum[blockIdx.x] = s;
    }
}

__global__ void scan2_kernel(int* __restrict__ bsum, int* __restrict__ rowptr, int nb, int n) {
    int t = threadIdx.x;  // 64 threads
    int v = (t < nb) ? bsum[t] : 0;
    int incl = wave_incl_scan(v);
    if (t < nb) bsum[t] = incl - v;
    if (t == 63) rowptr[n] = incl;
}

__global__ void scan3_kernel(const int* __restrict__ deg, const int* __restrict__ bsum,
                             int* __restrict__ rowptr, int* __restrict__ cursor,
                             float* __restrict__ dinv, int n) {
    __shared__ int wsum[16];
    int t = threadIdx.x;
    int i = blockIdx.x * 1024 + t;
    int v = (i < n) ? deg[i] : 0;
    int incl = wave_incl_scan(v);
    int wid = t >> 6;
    if ((t & 63) == 63) wsum[wid] = incl;
    __syncthreads();
    if (t == 0) {
        int run = 0;
#pragma unroll
        for (int w = 0; w < 16; ++w) { int x = wsum[w]; wsum[w] = run; run += x; }
    }
    __syncthreads();
    if (i < n) {
        int excl = incl - v + wsum[wid] + bsum[blockIdx.x];
        rowptr[i] = excl;
        cursor[i] = excl;
        dinv[i] = rsqrtf((float)(v + 1));  // +1 self-loop
    }
}

// ---------- CSR fill ----------
__global__ void fill_kernel(const int* __restrict__ src, const int* __restrict__ dst,
                            int* __restrict__ cursor, int* __restrict__ csr, int nE) {
    int e = blockIdx.x * blockDim.x + threadIdx.x;
    if (e >= nE) return;
    int pos = atomicAdd(&cursor[dst[e]], 1);
    csr[pos] = src[e];
}

// ---------- GEMM: Hs[r] = bf16( (X[r,:] @ W) * dinv[r] ), packed pairs ----------
template <int ROWS, bool BF16IN>
__global__ __launch_bounds__(64) void gemm_kernel(const void* __restrict__ Xv,
                                                  const float* __restrict__ W,
                                                  const float* __restrict__ dinv,
                                                  uint* __restrict__ Hs, int M) {
    __shared__ float xs[ROWS][DIM];
    const int t = threadIdx.x;
    const int r0 = blockIdx.x * ROWS;
#pragma unroll
    for (int r = 0; r < ROWS; ++r) {
        int row = r0 + r;
        if (row < M) {
            if (BF16IN) {
                uint u = ((const uint*)Xv)[(size_t)row * 64 + t];
                xs[r][2 * t] = bflo(u); xs[r][2 * t + 1] = bfhi(u);
            } else {
                float2 v = ((const float2*)Xv)[(size_t)row * 64 + t];
                xs[r][2 * t] = v.x; xs[r][2 * t + 1] = v.y;
            }
        } else {
            xs[r][2 * t] = 0.0f; xs[r][2 * t + 1] = 0.0f;
        }
    }
    __syncthreads();
    float2 acc[ROWS];
#pragma unroll
    for (int r = 0; r < ROWS; ++r) acc[r] = make_float2(0.0f, 0.0f);
    const float2* Wp = (const float2*)W;
    float2 w[4];
#pragma unroll
    for (int j = 0; j < 4; ++j) w[j] = Wp[j * 64 + t];
    for (int k4 = 0; k4 < DIM; k4 += 4) {
        float2 wn[4];
        if (k4 + 4 < DIM) {
#pragma unroll
            for (int j = 0; j < 4; ++j) wn[j] = Wp[(k4 + 4 + j) * 64 + t];
        }
#pragma unroll
        for (int r = 0; r < ROWS; ++r) {
            float4 xv = *(const float4*)&xs[r][k4];
            acc[r].x += xv.x * w[0].x; acc[r].y += xv.x * w[0].y;
            acc[r].x += xv.y * w[1].x; acc[r].y += xv.y * w[1].y;
            acc[r].x += xv.z * w[2].x; acc[r].y += xv.z * w[2].y;
            acc[r].x += xv.w * w[3].x; acc[r].y += xv.w * w[3].y;
        }
        if (k4 + 4 < DIM) {
#pragma unroll
            for (int j = 0; j < 4; ++j) w[j] = wn[j];
        }
    }
#pragma unroll
    for (int r = 0; r < ROWS; ++r) {
        int row = r0 + r;
        if (row < M) {
            float di = dinv[row];
            Hs[(size_t)row * 64 + t] = packbf2(acc[r].x * di, acc[r].y * di);
        }
    }
}

// ---------- gather layer 1: A[i] = bf16(relu(dinv[i]*(Hs[i]+sum Hs[nbr]) + b1)) ----------
__global__ __launch_bounds__(256) void gather1_kernel(const uint* __restrict__ Hs,
        const int* __restrict__ rowptr, const int* __restrict__ csr,
        const float* __restrict__ dinv, const float* __restrict__ b1,
        uint* __restrict__ A, int n) {
    int i = blockIdx.x * 4 + (threadIdx.x >> 6);
    int t = threadIdx.x & 63;
    if (i >= n) return;
    int e = rowptr[i], end = rowptr[i + 1];
    uint u = Hs[(size_t)i * 64 + t];  // self-loop
    float ax = bflo(u), ay = bfhi(u);
    for (; e + 8 <= end; e += 8) {
        int s0 = csr[e],     s1 = csr[e + 1], s2 = csr[e + 2], s3 = csr[e + 3];
        int s4 = csr[e + 4], s5 = csr[e + 5], s6 = csr[e + 6], s7 = csr[e + 7];
        uint u0 = Hs[(size_t)s0 * 64 + t];
        uint u1 = Hs[(size_t)s1 * 64 + t];
        uint u2 = Hs[(size_t)s2 * 64 + t];
        uint u3 = Hs[(size_t)s3 * 64 + t];
        uint u4 = Hs[(size_t)s4 * 64 + t];
        uint u5 = Hs[(size_t)s5 * 64 + t];
        uint u6 = Hs[(size_t)s6 * 64 + t];
        uint u7 = Hs[(size_t)s7 * 64 + t];
        ax += ((bflo(u0) + bflo(u1)) + (bflo(u2) + bflo(u3)))
            + ((bflo(u4) + bflo(u5)) + (bflo(u6) + bflo(u7)));
        ay += ((bfhi(u0) + bfhi(u1)) + (bfhi(u2) + bfhi(u3)))
            + ((bfhi(u4) + bfhi(u5)) + (bfhi(u6) + bfhi(u7)));
    }
    for (; e + 4 <= end; e += 4) {
        int s0 = csr[e], s1 = csr[e + 1], s2 = csr[e + 2], s3 = csr[e + 3];
        uint u0 = Hs[(size_t)s0 * 64 + t];
        uint u1 = Hs[(size_t)s1 * 64 + t];
        uint u2 = Hs[(size_t)s2 * 64 + t];
        uint u3 = Hs[(size_t)s3 * 64 + t];
        ax += (bflo(u0) + bflo(u1)) + (bflo(u2) + bflo(u3));
        ay += (bfhi(u0) + bfhi(u1)) + (bfhi(u2) + bfhi(u3));
    }
    for (; e < end; ++e) {
        uint uu = Hs[(size_t)csr[e] * 64 + t];
        ax += bflo(uu); ay += bfhi(uu);
    }
    float di = dinv[i];
    float2 b = *(const float2*)(b1 + 2 * t);
    A[(size_t)i * 64 + t] = packbf2(fmaxf(di * ax + b.x, 0.0f),
                                    fmaxf(di * ay + b.y, 0.0f));
}

// ---------- gather layer 2 + pooled-merge atomics ----------
// 8 waves/block = 8 consecutive nodes; batch sorted -> few distinct graph ids per block.
__global__ __launch_bounds__(512) void gather2_kernel(const uint* __restrict__ Hs,
        const int* __restrict__ rowptr, const int* __restrict__ csr,
        const float* __restrict__ dinv, const int* __restrict__ batch,
        float* __restrict__ out, int n) {
    __shared__ float sh[8][DIM];
    __shared__ int sgid[8];
    int w = threadIdx.x >> 6;
    int t = threadIdx.x & 63;
    int i = blockIdx.x * 8 + w;
    if (i < n) {
        int e = rowptr[i], end = rowptr[i + 1];
        uint u = Hs[(size_t)i * 64 + t];
        float ax = bflo(u), ay = bfhi(u);
        for (; e + 8 <= end; e += 8) {
            int s0 = csr[e],     s1 = csr[e + 1], s2 = csr[e + 2], s3 = csr[e + 3];
            int s4 = csr[e + 4], s5 = csr[e + 5], s6 = csr[e + 6], s7 = csr[e + 7];
            uint u0 = Hs[(size_t)s0 * 64 + t];
            uint u1 = Hs[(size_t)s1 * 64 + t];
            uint u2 = Hs[(size_t)s2 * 64 + t];
            uint u3 = Hs[(size_t)s3 * 64 + t];
            uint u4 = Hs[(size_t)s4 * 64 + t];
            uint u5 = Hs[(size_t)s5 * 64 + t];
            uint u6 = Hs[(size_t)s6 * 64 + t];
            uint u7 = Hs[(size_t)s7 * 64 + t];
            ax += ((bflo(u0) + bflo(u1)) + (bflo(u2) + bflo(u3)))
                + ((bflo(u4) + bflo(u5)) + (bflo(u6) + bflo(u7)));
            ay += ((bfhi(u0) + bfhi(u1)) + (bfhi(u2) + bfhi(u3)))
                + ((bfhi(u4) + bfhi(u5)) + (bfhi(u6) + bfhi(u7)));
        }
        for (; e + 4 <= end; e += 4) {
            int s0 = csr[e], s1 = csr[e + 1], s2 = csr[e + 2], s3 = csr[e + 3];
            uint u0 = Hs[(size_t)s0 * 64 + t];
            uint u1 = Hs[(size_t)s1 * 64 + t];
            uint u2 = Hs[(size_t)s2 * 64 + t];
            uint u3 = Hs[(size_t)s3 * 64 + t];
            ax += (bflo(u0) + bflo(u1)) + (bflo(u2) + bflo(u3));
            ay += (bfhi(u0) + bfhi(u1)) + (bfhi(u2) + bfhi(u3));
        }
        for (; e < end; ++e) {
            uint uu = Hs[(size_t)csr[e] * 64 + t];
            ax += bflo(uu); ay += bfhi(uu);
        }
        float di = dinv[i];
        sh[w][2 * t]     = di * ax;
        sh[w][2 * t + 1] = di * ay;
        if (t == 0) sgid[w] = batch[i];
    } else if (t == 0) {
        sgid[w] = -1;
    }
    __syncthreads();
    if (threadIdx.x < DIM) {
        int d = threadIdx.x;
        int curg = -1; float run = 0.0f;
#pragma unroll
        for (int r = 0; r < 8; ++r) {
            int g = sgid[r];
            if (g < 0) continue;
            if (g != curg) {
                if (curg >= 0) atomicAdd(&out[(size_t)curg * DIM + d], run);
                curg = g; run = sh[r][d];
            } else {
                run += sh[r][d];
            }
        }
        if (curg >= 0) atomicAdd(&out[(size_t)curg * DIM + d], run);
    }
}

// ---------- finalize ----------
__global__ void fin_kernel(float* __restrict__ out, const int* __restrict__ cnt,
                           const float* __restrict__ b2, int nG) {
    int tid = blockIdx.x * blockDim.x + threadIdx.x;
    int g = tid >> 7;
    int d = tid & (DIM - 1);
    if (g >= nG) return;
    float c = (float)cnt[g];
    out[tid] = (out[tid] + c * b2[d]) / fmaxf(c, 1.0f);
}

extern "C" void kernel_launch(void* const* d_in, const int* in_sizes, int n_in,
                              void* d_out, int out_size, void* d_ws, size_t ws_size,
                              hipStream_t stream) {
    const float* x     = (const float*)d_in[0];
    const int*   ei    = (const int*)d_in[1];
    const int*   batch = (const int*)d_in[2];
    const float* W1    = (const float*)d_in[3];
    const float* b1    = (const float*)d_in[4];
    const float* W2    = (const float*)d_in[5];
    const float* b2    = (const float*)d_in[6];
    float* out = (float*)d_out;

    const int n  = in_sizes[0] / DIM;   // 50000
    const int nE = in_sizes[1] / 2;     // 800000
    const int nG = out_size / DIM;      // 512

    const int* src = ei;
    const int* dst = ei + nE;

    const size_t packBytes = (size_t)n * 64 * sizeof(uint);  // 12.8 MB
    char* ws = (char*)d_ws;
    size_t off = 0;
    uint*  Hs     = (uint*)(ws + off); off += packBytes;
    uint*  A      = (uint*)(ws + off); off += packBytes;
    int*   deg    = (int*)(ws + off);  off += (size_t)n * 4;
    int*   cnt    = (int*)(ws + off);  off += (size_t)nG * 4;   // adjacent to deg: one memset
    float* dinv   = (float*)(ws + off); off += (size_t)n * 4;
    int*   rowptr = (int*)(ws + off);  off += (size_t)(n + 1) * 4;
    int*   cursor = (int*)(ws + off);  off += (size_t)n * 4;
    int*   bsum   = (int*)(ws + off);  off += 256;
    int*   csr    = (int*)(ws + off);  off += (size_t)nE * 4;

    const int B = 256;
    const int nb = (n + 1023) / 1024;        // 49 (<= 64)
    const int ROWS = 16;
    const int gemmGrid = (n + ROWS - 1) / ROWS;

    hipMemsetAsync(deg, 0, (size_t)(n + nG) * 4, stream);
    hipMemsetAsync(out, 0, (size_t)out_size * sizeof(float), stream);

    degcnt_kernel<<<(nE + B - 1) / B, B, 0, stream>>>(dst, deg, nE, batch, cnt, n);
    scan1_kernel<<<nb, 1024, 0, stream>>>(deg, bsum, n);
    scan2_kernel<<<1, 64, 0, stream>>>(bsum, rowptr, nb, n);
    scan3_kernel<<<nb, 1024, 0, stream>>>(deg, bsum, rowptr, cursor, dinv, n);
    fill_kernel<<<(nE + B - 1) / B, B, 0, stream>>>(src, dst, cursor, csr, nE);

    // Layer 1
    gemm_kernel<16, false><<<gemmGrid, 64, 0, stream>>>(x, W1, dinv, Hs, n);
    gather1_kernel<<<(n + 3) / 4, 256, 0, stream>>>(Hs, rowptr, csr, dinv, b1, A, n);

    // Layer 2
    gemm_kernel<16, true><<<gemmGrid, 64, 0, stream>>>(A, W2, dinv, Hs, n);
    gather2_kernel<<<(n + 7) / 8, 512, 0, stream>>>(Hs, rowptr, csr, dinv, batch, out, n);

    fin_kernel<<<(nG * DIM + B - 1) / B, B, 0, stream>>>(out, cnt, b2, nG);
}

// Round 6
// 235.824 us; speedup vs baseline: 3.8459x; 1.2140x over previous
//
#include <hip/hip_runtime.h>

typedef unsigned int uint;
#define DIM 128
#define NCH 64      // edge chunks for CSR build
#define MAXG 512    // LDS bins for graph-count histogram

// ---------- bf16 pack/unpack helpers ----------
__device__ inline float bflo(uint u) { return __uint_as_float(u << 16); }
__device__ inline float bfhi(uint u) { return __uint_as_float(u & 0xffff0000u); }
__device__ inline uint packbf2(float a, float b) {
    uint ua = __float_as_uint(a), ub = __float_as_uint(b);
    ua = (ua + 0x7fffu + ((ua >> 16) & 1u)) >> 16;
    ub = (ub + 0x7fffu + ((ub >> 16) & 1u)) & 0xffff0000u;
    return ua | ub;
}

// ---------- graph-count histogram (batch sorted -> few bins/block) ----------
__global__ __launch_bounds__(256) void cnt_kernel(const int* __restrict__ batch,
                                                  int* __restrict__ cnt, int n, int nG) {
    __shared__ int h[MAXG];
    for (int j = threadIdx.x; j < nG; j += 256) h[j] = 0;
    __syncthreads();
    int chunk = (n + gridDim.x - 1) / gridDim.x;
    int lo = blockIdx.x * chunk;
    int hi = min(n, lo + chunk);
    for (int i = lo + threadIdx.x; i < hi; i += 256) atomicAdd(&h[batch[i]], 1);
    __syncthreads();
    for (int j = threadIdx.x; j < nG; j += 256) {
        int v = h[j];
        if (v) atomicAdd(&cnt[j], v);
    }
}

// ---------- chunked packed histogram: part[c][node] = #edges in chunk c with dst=node ----------
// packed 2 nodes per uint (lo16 = even node, hi16 = odd node)
__global__ __launch_bounds__(256) void hist_kernel(const int* __restrict__ dst,
                                                   uint* __restrict__ part,
                                                   int nE, int n, int WPC) {
    extern __shared__ uint h[];
    const int nw = (n + 1) >> 1;
    for (int j = threadIdx.x; j < nw; j += 256) h[j] = 0;
    __syncthreads();
    int chunk = (((nE + NCH - 1) / NCH) + 3) & ~3;
    int lo = blockIdx.x * chunk;
    int hi = min(nE, lo + chunk);
    int hiA = lo + ((hi - lo) & ~3);
    for (int e = lo + threadIdx.x * 4; e < hiA; e += 1024) {
        int4 v = *(const int4*)(dst + e);
        atomicAdd(&h[v.x >> 1], 1u << ((v.x & 1) * 16));
        atomicAdd(&h[v.y >> 1], 1u << ((v.y & 1) * 16));
        atomicAdd(&h[v.z >> 1], 1u << ((v.z & 1) * 16));
        atomicAdd(&h[v.w >> 1], 1u << ((v.w & 1) * 16));
    }
    for (int e = hiA + threadIdx.x; e < hi; e += 256) {
        int d = dst[e];
        atomicAdd(&h[d >> 1], 1u << ((d & 1) * 16));
    }
    __syncthreads();
    uint* pw = part + (size_t)blockIdx.x * WPC;
    for (int j = threadIdx.x; j < nw; j += 256) pw[j] = h[j];
}

// ---------- reduce: deg[node] = sum_c part[c][node]; part[c] <- exclusive prefix over c ----------
__global__ void reduce_kernel(uint* __restrict__ part, int* __restrict__ deg, int n, int WPC) {
    int j = blockIdx.x * blockDim.x + threadIdx.x;
    int nw = (n + 1) >> 1;
    if (j >= nw) return;
    uint run = 0;
#pragma unroll
    for (int c = 0; c < NCH; ++c) {
        size_t idx = (size_t)c * WPC + j;
        uint v = part[idx];
        part[idx] = run;
        run += v;  // packed add; per-half sums << 65536
    }
    deg[2 * j] = (int)(run & 0xffffu);
    if (2 * j + 1 < n) deg[2 * j + 1] = (int)(run >> 16);
}

// ---------- multi-block exclusive scan: deg -> rowptr (+ dinv) ----------
__device__ inline int wave_incl_scan(int v) {
    int lane = threadIdx.x & 63;
#pragma unroll
    for (int off = 1; off < 64; off <<= 1) {
        int u = __shfl_up(v, off, 64);
        if (lane >= off) v += u;
    }
    return v;
}

__global__ void scan1_kernel(const int* __restrict__ deg, int* __restrict__ bsum, int n) {
    __shared__ int wsum[16];
    int t = threadIdx.x;
    int i = blockIdx.x * 1024 + t;
    int v = (i < n) ? deg[i] : 0;
#pragma unroll
    for (int off = 32; off > 0; off >>= 1) v += __shfl_down(v, off, 64);
    if ((t & 63) == 0) wsum[t >> 6] = v;
    __syncthreads();
    if (t == 0) {
        int s = 0;
#pragma unroll
        for (int w = 0; w < 16; ++w) s += wsum[w];
        bsum[blockIdx.x] = s;
    }
}

__global__ void scan2_kernel(int* __restrict__ bsum, int* __restrict__ rowptr, int nb, int n) {
    int t = threadIdx.x;  // 64 threads
    int v = (t < nb) ? bsum[t] : 0;
    int incl = wave_incl_scan(v);
    if (t < nb) bsum[t] = incl - v;
    if (t == 63) rowptr[n] = incl;
}

__global__ void scan3_kernel(const int* __restrict__ deg, const int* __restrict__ bsum,
                             int* __restrict__ rowptr, float* __restrict__ dinv, int n) {
    __shared__ int wsum[16];
    int t = threadIdx.x;
    int i = blockIdx.x * 1024 + t;
    int v = (i < n) ? deg[i] : 0;
    int incl = wave_incl_scan(v);
    int wid = t >> 6;
    if ((t & 63) == 63) wsum[wid] = incl;
    __syncthreads();
    if (t == 0) {
        int run = 0;
#pragma unroll
        for (int w = 0; w < 16; ++w) { int x = wsum[w]; wsum[w] = run; run += x; }
    }
    __syncthreads();
    if (i < n) {
        rowptr[i] = incl - v + wsum[wid] + bsum[blockIdx.x];
        dinv[i] = rsqrtf((float)(v + 1));  // +1 self-loop
    }
}

// ---------- CSR fill: LDS cursor + chunk prefix, no global atomics ----------
__global__ __launch_bounds__(256) void fill_kernel(const int* __restrict__ src,
                                                   const int* __restrict__ dst,
                                                   const uint* __restrict__ part,
                                                   const int* __restrict__ rowptr,
                                                   int* __restrict__ csr,
                                                   int nE, int n, int WPC) {
    extern __shared__ uint cur[];
    const int nw = (n + 1) >> 1;
    for (int j = threadIdx.x; j < nw; j += 256) cur[j] = 0;
    __syncthreads();
    const uint* P = part + (size_t)blockIdx.x * WPC;
    int chunk = (((nE + NCH - 1) / NCH) + 3) & ~3;
    int lo = blockIdx.x * chunk;
    int hi = min(nE, lo + chunk);
    int hiA = lo + ((hi - lo) & ~3);
    for (int e = lo + threadIdx.x * 4; e < hiA; e += 1024) {
        int4 d4 = *(const int4*)(dst + e);
        int4 s4 = *(const int4*)(src + e);
        int dd[4] = {d4.x, d4.y, d4.z, d4.w};
        int ss[4] = {s4.x, s4.y, s4.z, s4.w};
#pragma unroll
        for (int k = 0; k < 4; ++k) {
            int d = dd[k];
            uint sh = (uint)(d & 1) * 16u;
            uint old = atomicAdd(&cur[d >> 1], 1u << sh);
            uint local = (old >> sh) & 0xffffu;
            uint pre = (P[d >> 1] >> sh) & 0xffffu;
            csr[rowptr[d] + (int)pre + (int)local] = ss[k];
        }
    }
    for (int e = hiA + threadIdx.x; e < hi; e += 256) {
        int d = dst[e];
        uint sh = (uint)(d & 1) * 16u;
        uint old = atomicAdd(&cur[d >> 1], 1u << sh);
        uint local = (old >> sh) & 0xffffu;
        uint pre = (P[d >> 1] >> sh) & 0xffffu;
        csr[rowptr[d] + (int)pre + (int)local] = src[e];
    }
}

// ---------- GEMM: Hs[r] = bf16( (X[r,:] @ W) * dinv[r] ), packed pairs ----------
template <int ROWS, bool BF16IN>
__global__ __launch_bounds__(64) void gemm_kernel(const void* __restrict__ Xv,
                                                  const float* __restrict__ W,
                                                  const float* __restrict__ dinv,
                                                  uint* __restrict__ Hs, int M) {
    __shared__ float xs[ROWS][DIM];
    const int t = threadIdx.x;
    const int r0 = blockIdx.x * ROWS;
#pragma unroll
    for (int r = 0; r < ROWS; ++r) {
        int row = r0 + r;
        if (row < M) {
            if (BF16IN) {
                uint u = ((const uint*)Xv)[(size_t)row * 64 + t];
                xs[r][2 * t] = bflo(u); xs[r][2 * t + 1] = bfhi(u);
            } else {
                float2 v = ((const float2*)Xv)[(size_t)row * 64 + t];
                xs[r][2 * t] = v.x; xs[r][2 * t + 1] = v.y;
            }
        } else {
            xs[r][2 * t] = 0.0f; xs[r][2 * t + 1] = 0.0f;
        }
    }
    __syncthreads();
    float2 acc[ROWS];
#pragma unroll
    for (int r = 0; r < ROWS; ++r) acc[r] = make_float2(0.0f, 0.0f);
    const float2* Wp = (const float2*)W;
    float2 w[4];
#pragma unroll
    for (int j = 0; j < 4; ++j) w[j] = Wp[j * 64 + t];
    for (int k4 = 0; k4 < DIM; k4 += 4) {
        float2 wn[4];
        if (k4 + 4 < DIM) {
#pragma unroll
            for (int j = 0; j < 4; ++j) wn[j] = Wp[(k4 + 4 + j) * 64 + t];
        }
#pragma unroll
        for (int r = 0; r < ROWS; ++r) {
            float4 xv = *(const float4*)&xs[r][k4];
            acc[r].x += xv.x * w[0].x; acc[r].y += xv.x * w[0].y;
            acc[r].x += xv.y * w[1].x; acc[r].y += xv.y * w[1].y;
            acc[r].x += xv.z * w[2].x; acc[r].y += xv.z * w[2].y;
            acc[r].x += xv.w * w[3].x; acc[r].y += xv.w * w[3].y;
        }
        if (k4 + 4 < DIM) {
#pragma unroll
            for (int j = 0; j < 4; ++j) w[j] = wn[j];
        }
    }
#pragma unroll
    for (int r = 0; r < ROWS; ++r) {
        int row = r0 + r;
        if (row < M) {
            float di = dinv[row];
            Hs[(size_t)row * 64 + t] = packbf2(acc[r].x * di, acc[r].y * di);
        }
    }
}

// ---------- gather body (shared by both layers) ----------
__device__ inline void gather_row(const uint* __restrict__ Hs, const int* __restrict__ csr,
                                  int e, int end, int t, float& ax, float& ay) {
    for (; e + 16 <= end; e += 16) {
        uint uu[16];
#pragma unroll
        for (int k = 0; k < 16; ++k) uu[k] = Hs[(size_t)csr[e + k] * 64 + t];
#pragma unroll
        for (int k = 0; k < 16; ++k) { ax += bflo(uu[k]); ay += bfhi(uu[k]); }
    }
    for (; e + 4 <= end; e += 4) {
        uint uu[4];
#pragma unroll
        for (int k = 0; k < 4; ++k) uu[k] = Hs[(size_t)csr[e + k] * 64 + t];
#pragma unroll
        for (int k = 0; k < 4; ++k) { ax += bflo(uu[k]); ay += bfhi(uu[k]); }
    }
    for (; e < end; ++e) {
        uint uu = Hs[(size_t)csr[e] * 64 + t];
        ax += bflo(uu); ay += bfhi(uu);
    }
}

// ---------- gather layer 1: A[i] = bf16(relu(dinv[i]*(Hs[i]+sum Hs[nbr]) + b1)) ----------
__global__ __launch_bounds__(256) void gather1_kernel(const uint* __restrict__ Hs,
        const int* __restrict__ rowptr, const int* __restrict__ csr,
        const float* __restrict__ dinv, const float* __restrict__ b1,
        uint* __restrict__ A, int n) {
    int i = blockIdx.x * 4 + (threadIdx.x >> 6);
    int t = threadIdx.x & 63;
    if (i >= n) return;
    uint u = Hs[(size_t)i * 64 + t];  // self-loop
    float ax = bflo(u), ay = bfhi(u);
    gather_row(Hs, csr, rowptr[i], rowptr[i + 1], t, ax, ay);
    float di = dinv[i];
    float2 b = *(const float2*)(b1 + 2 * t);
    A[(size_t)i * 64 + t] = packbf2(fmaxf(di * ax + b.x, 0.0f),
                                    fmaxf(di * ay + b.y, 0.0f));
}

// ---------- gather layer 2 + pooled-merge atomics ----------
__global__ __launch_bounds__(512) void gather2_kernel(const uint* __restrict__ Hs,
        const int* __restrict__ rowptr, const int* __restrict__ csr,
        const float* __restrict__ dinv, const int* __restrict__ batch,
        float* __restrict__ out, int n) {
    __shared__ float sh[8][DIM];
    __shared__ int sgid[8];
    int w = threadIdx.x >> 6;
    int t = threadIdx.x & 63;
    int i = blockIdx.x * 8 + w;
    if (i < n) {
        uint u = Hs[(size_t)i * 64 + t];
        float ax = bflo(u), ay = bfhi(u);
        gather_row(Hs, csr, rowptr[i], rowptr[i + 1], t, ax, ay);
        float di = dinv[i];
        sh[w][2 * t]     = di * ax;
        sh[w][2 * t + 1] = di * ay;
        if (t == 0) sgid[w] = batch[i];
    } else if (t == 0) {
        sgid[w] = -1;
    }
    __syncthreads();
    if (threadIdx.x < DIM) {
        int d = threadIdx.x;
        int curg = -1; float run = 0.0f;
#pragma unroll
        for (int r = 0; r < 8; ++r) {
            int g = sgid[r];
            if (g < 0) continue;
            if (g != curg) {
                if (curg >= 0) atomicAdd(&out[(size_t)curg * DIM + d], run);
                curg = g; run = sh[r][d];
            } else {
                run += sh[r][d];
            }
        }
        if (curg >= 0) atomicAdd(&out[(size_t)curg * DIM + d], run);
    }
}

// ---------- finalize ----------
__global__ void fin_kernel(float* __restrict__ out, const int* __restrict__ cnt,
                           const float* __restrict__ b2, int nG) {
    int tid = blockIdx.x * blockDim.x + threadIdx.x;
    int g = tid >> 7;
    int d = tid & (DIM - 1);
    if (g >= nG) return;
    float c = (float)cnt[g];
    out[tid] = (out[tid] + c * b2[d]) / fmaxf(c, 1.0f);
}

extern "C" void kernel_launch(void* const* d_in, const int* in_sizes, int n_in,
                              void* d_out, int out_size, void* d_ws, size_t ws_size,
                              hipStream_t stream) {
    const float* x     = (const float*)d_in[0];
    const int*   ei    = (const int*)d_in[1];
    const int*   batch = (const int*)d_in[2];
    const float* W1    = (const float*)d_in[3];
    const float* b1    = (const float*)d_in[4];
    const float* W2    = (const float*)d_in[5];
    const float* b2    = (const float*)d_in[6];
    float* out = (float*)d_out;

    const int n  = in_sizes[0] / DIM;   // 50000
    const int nE = in_sizes[1] / 2;     // 800000
    const int nG = out_size / DIM;      // 512

    const int* src = ei;
    const int* dst = ei + nE;

    const int nw  = (n + 1) >> 1;             // packed words per histogram
    const int WPC = (nw + 3) & ~3;            // 16B-aligned row stride
    const size_t packBytes = (size_t)n * 64 * sizeof(uint);  // 12.8 MB
    const size_t ldsBytes  = (size_t)WPC * 4; // ~100 KB dynamic LDS

    char* ws = (char*)d_ws;
    size_t off = 0;
    auto alloc = [&](size_t bytes) { void* p = ws + off; off = (off + bytes + 255) & ~(size_t)255; return p; };
    uint*  Hs     = (uint*)alloc(packBytes);
    uint*  A      = (uint*)alloc(packBytes);
    int*   deg    = (int*)alloc((size_t)n * 4);
    int*   cnt    = (int*)alloc((size_t)nG * 4);
    float* dinv   = (float*)alloc((size_t)n * 4);
    int*   rowptr = (int*)alloc((size_t)(n + 1) * 4);
    int*   bsum   = (int*)alloc(256);
    uint*  part   = (uint*)alloc((size_t)NCH * WPC * 4);  // 6.4 MB
    int*   csr    = (int*)alloc((size_t)nE * 4);

    const int B = 256;
    const int nb = (n + 1023) / 1024;        // 49 (<= 64)
    const int ROWS = 16;
    const int gemmGrid = (n + ROWS - 1) / ROWS;

    hipMemsetAsync(cnt, 0, (size_t)nG * 4, stream);
    hipMemsetAsync(out, 0, (size_t)out_size * sizeof(float), stream);

    cnt_kernel<<<64, 256, 0, stream>>>(batch, cnt, n, nG);
    hist_kernel<<<NCH, 256, ldsBytes, stream>>>(dst, part, nE, n, WPC);
    reduce_kernel<<<(nw + B - 1) / B, B, 0, stream>>>(part, deg, n, WPC);
    scan1_kernel<<<nb, 1024, 0, stream>>>(deg, bsum, n);
    scan2_kernel<<<1, 64, 0, stream>>>(bsum, rowptr, nb, n);
    scan3_kernel<<<nb, 1024, 0, stream>>>(deg, bsum, rowptr, dinv, n);
    fill_kernel<<<NCH, 256, ldsBytes, stream>>>(src, dst, part, rowptr, csr, nE, n, WPC);

    // Layer 1
    gemm_kernel<16, false><<<gemmGrid, 64, 0, stream>>>(x, W1, dinv, Hs, n);
    gather1_kernel<<<(n + 3) / 4, 256, 0, stream>>>(Hs, rowptr, csr, dinv, b1, A, n);

    // Layer 2
    gemm_kernel<16, true><<<gemmGrid, 64, 0, stream>>>(A, W2, dinv, Hs, n);
    gather2_kernel<<<(n + 7) / 8, 512, 0, stream>>>(Hs, rowptr, csr, dinv, batch, out, n);

    fin_kernel<<<(nG * DIM + B - 1) / B, B, 0, stream>>>(out, cnt, b2, nG);
}

// Round 7
// 222.553 us; speedup vs baseline: 4.0753x; 1.0596x over previous
//
#include <hip/hip_runtime.h>

typedef unsigned int uint;
#define DIM 128
#define NCH 256     // edge chunks for CSR build (one block per CU)
#define MAXG 512    // LDS bins for graph-count histogram

typedef __attribute__((ext_vector_type(8))) short bf16x8;
typedef __attribute__((ext_vector_type(4))) float f32x4;

// ---------- bf16 pack/unpack helpers ----------
__device__ inline float bflo(uint u) { return __uint_as_float(u << 16); }
__device__ inline float bfhi(uint u) { return __uint_as_float(u & 0xffff0000u); }
__device__ inline uint packbf2(float a, float b) {
    uint ua = __float_as_uint(a), ub = __float_as_uint(b);
    ua = (ua + 0x7fffu + ((ua >> 16) & 1u)) >> 16;
    ub = (ub + 0x7fffu + ((ub >> 16) & 1u)) & 0xffff0000u;
    return ua | ub;
}

// ---------- prep: x f32 -> packed bf16 pairs ----------
__global__ void cvtx_kernel(const float* __restrict__ x, uint* __restrict__ xb, int total) {
    int i = blockIdx.x * blockDim.x + threadIdx.x;
    if (i < total) {
        float2 v = ((const float2*)x)[i];
        xb[i] = packbf2(v.x, v.y);
    }
}

// ---------- prep: W[k][c] f32 -> Wt[c][k] packed bf16 pairs ----------
__global__ void cvtw_kernel(const float* __restrict__ W, uint* __restrict__ Wt) {
    int idx = blockIdx.x * 256 + threadIdx.x;  // 0..8191
    int c = idx >> 6;
    int kw = idx & 63;
    float a = W[(2 * kw) * DIM + c];
    float b = W[(2 * kw + 1) * DIM + c];
    Wt[c * 64 + kw] = packbf2(a, b);
}

// ---------- graph-count histogram ----------
__global__ __launch_bounds__(256) void cnt_kernel(const int* __restrict__ batch,
                                                  int* __restrict__ cnt, int n, int nG) {
    __shared__ int h[MAXG];
    for (int j = threadIdx.x; j < nG; j += 256) h[j] = 0;
    __syncthreads();
    int chunk = (n + gridDim.x - 1) / gridDim.x;
    int lo = blockIdx.x * chunk;
    int hi = min(n, lo + chunk);
    for (int i = lo + threadIdx.x; i < hi; i += 256) atomicAdd(&h[batch[i]], 1);
    __syncthreads();
    for (int j = threadIdx.x; j < nG; j += 256) {
        int v = h[j];
        if (v) atomicAdd(&cnt[j], v);
    }
}

// ---------- chunked packed histogram ----------
__global__ __launch_bounds__(256) void hist_kernel(const int* __restrict__ dst,
                                                   uint* __restrict__ part,
                                                   int nE, int n, int WPC) {
    extern __shared__ uint h[];
    const int nw = (n + 1) >> 1;
    for (int j = threadIdx.x; j < nw; j += 256) h[j] = 0;
    __syncthreads();
    int chunk = (((nE + NCH - 1) / NCH) + 3) & ~3;
    int lo = blockIdx.x * chunk;
    int hi = min(nE, lo + chunk);
    int hiA = lo + ((hi - lo) & ~3);
    for (int e = lo + threadIdx.x * 4; e < hiA; e += 1024) {
        int4 v = *(const int4*)(dst + e);
        atomicAdd(&h[v.x >> 1], 1u << ((v.x & 1) * 16));
        atomicAdd(&h[v.y >> 1], 1u << ((v.y & 1) * 16));
        atomicAdd(&h[v.z >> 1], 1u << ((v.z & 1) * 16));
        atomicAdd(&h[v.w >> 1], 1u << ((v.w & 1) * 16));
    }
    for (int e = hiA + threadIdx.x; e < hi; e += 256) {
        int d = dst[e];
        atomicAdd(&h[d >> 1], 1u << ((d & 1) * 16));
    }
    __syncthreads();
    uint* pw = part + (size_t)blockIdx.x * WPC;
    for (int j = threadIdx.x; j < nw; j += 256) pw[j] = h[j];
}

// ---------- reduce: deg = sum_c part[c]; part[c] <- exclusive chunk prefix ----------
__global__ void reduce_kernel(uint* __restrict__ part, int* __restrict__ deg, int n, int WPC) {
    int j = blockIdx.x * blockDim.x + threadIdx.x;
    int nw = (n + 1) >> 1;
    if (j >= nw) return;
    uint run = 0;
#pragma unroll 8
    for (int c = 0; c < NCH; ++c) {
        size_t idx = (size_t)c * WPC + j;
        uint v = part[idx];
        part[idx] = run;
        run += v;  // packed add; per-half sums << 65536
    }
    deg[2 * j] = (int)(run & 0xffffu);
    if (2 * j + 1 < n) deg[2 * j + 1] = (int)(run >> 16);
}

// ---------- multi-block exclusive scan ----------
__device__ inline int wave_incl_scan(int v) {
    int lane = threadIdx.x & 63;
#pragma unroll
    for (int off = 1; off < 64; off <<= 1) {
        int u = __shfl_up(v, off, 64);
        if (lane >= off) v += u;
    }
    return v;
}

__global__ void scan1_kernel(const int* __restrict__ deg, int* __restrict__ bsum, int n) {
    __shared__ int wsum[16];
    int t = threadIdx.x;
    int i = blockIdx.x * 1024 + t;
    int v = (i < n) ? deg[i] : 0;
#pragma unroll
    for (int off = 32; off > 0; off >>= 1) v += __shfl_down(v, off, 64);
    if ((t & 63) == 0) wsum[t >> 6] = v;
    __syncthreads();
    if (t == 0) {
        int s = 0;
#pragma unroll
        for (int w = 0; w < 16; ++w) s += wsum[w];
        bsum[blockIdx.x] = s;
    }
}

__global__ void scan2_kernel(int* __restrict__ bsum, int* __restrict__ rowptr, int nb, int n) {
    int t = threadIdx.x;  // 64 threads
    int v = (t < nb) ? bsum[t] : 0;
    int incl = wave_incl_scan(v);
    if (t < nb) bsum[t] = incl - v;
    if (t == 63) rowptr[n] = incl;
}

__global__ void scan3_kernel(const int* __restrict__ deg, const int* __restrict__ bsum,
                             int* __restrict__ rowptr, float* __restrict__ dinv, int n) {
    __shared__ int wsum[16];
    int t = threadIdx.x;
    int i = blockIdx.x * 1024 + t;
    int v = (i < n) ? deg[i] : 0;
    int incl = wave_incl_scan(v);
    int wid = t >> 6;
    if ((t & 63) == 63) wsum[wid] = incl;
    __syncthreads();
    if (t == 0) {
        int run = 0;
#pragma unroll
        for (int w = 0; w < 16; ++w) { int x = wsum[w]; wsum[w] = run; run += x; }
    }
    __syncthreads();
    if (i < n) {
        rowptr[i] = incl - v + wsum[wid] + bsum[blockIdx.x];
        dinv[i] = rsqrtf((float)(v + 1));  // +1 self-loop
    }
}

// ---------- CSR fill: LDS cursor + chunk prefix, no global atomics ----------
__global__ __launch_bounds__(256) void fill_kernel(const int* __restrict__ src,
                                                   const int* __restrict__ dst,
                                                   const uint* __restrict__ part,
                                                   const int* __restrict__ rowptr,
                                                   int* __restrict__ csr,
                                                   int nE, int n, int WPC) {
    extern __shared__ uint cur[];
    const int nw = (n + 1) >> 1;
    for (int j = threadIdx.x; j < nw; j += 256) cur[j] = 0;
    __syncthreads();
    const uint* P = part + (size_t)blockIdx.x * WPC;
    int chunk = (((nE + NCH - 1) / NCH) + 3) & ~3;
    int lo = blockIdx.x * chunk;
    int hi = min(nE, lo + chunk);
    int hiA = lo + ((hi - lo) & ~3);
    for (int e = lo + threadIdx.x * 4; e < hiA; e += 1024) {
        int4 d4 = *(const int4*)(dst + e);
        int4 s4 = *(const int4*)(src + e);
        int dd[4] = {d4.x, d4.y, d4.z, d4.w};
        int ss[4] = {s4.x, s4.y, s4.z, s4.w};
#pragma unroll
        for (int k = 0; k < 4; ++k) {
            int d = dd[k];
            uint sh = (uint)(d & 1) * 16u;
            uint old = atomicAdd(&cur[d >> 1], 1u << sh);
            uint local = (old >> sh) & 0xffffu;
            uint pre = (P[d >> 1] >> sh) & 0xffffu;
            csr[rowptr[d] + (int)pre + (int)local] = ss[k];
        }
    }
    for (int e = hiA + threadIdx.x; e < hi; e += 256) {
        int d = dst[e];
        uint sh = (uint)(d & 1) * 16u;
        uint old = atomicAdd(&cur[d >> 1], 1u << sh);
        uint local = (old >> sh) & 0xffffu;
        uint pre = (P[d >> 1] >> sh) & 0xffffu;
        csr[rowptr[d] + (int)pre + (int)local] = src[e];
    }
}

// ---------- MFMA GEMM: Hs[r] = bf16( (X[r,:] @ W) * dinv[r] ) ----------
// block = 256 thr (4 waves); 64 rows x 128 cols per block; whole K=128 in LDS.
// LDS unit-swizzle: 16B unit u at row r stored at u^(r&7) -> 2-way max on ds_read_b128.
__global__ __launch_bounds__(256) void gemm_mfma_kernel(const uint* __restrict__ Xb,
        const uint* __restrict__ Wt, const float* __restrict__ dinv,
        uint* __restrict__ Hs, int M) {
    __shared__ __align__(16) uint lw[8192];  // 32KB Wt[c][k]
    __shared__ __align__(16) uint lx[4096];  // 16KB X[r][k]
    const int tid = threadIdx.x;
    const int brow = blockIdx.x * 64;
#pragma unroll
    for (int p = 0; p < 16; ++p) {
        int j = p * 256 + tid;
        int r = j >> 6, kw = j & 63;
        int row = brow + r;
        uint v = (row < M) ? Xb[(size_t)row * 64 + kw] : 0u;
        lx[(r << 6) | (((kw >> 2) ^ (r & 7)) << 2) | (kw & 3)] = v;
    }
#pragma unroll
    for (int p = 0; p < 32; ++p) {
        int j = p * 256 + tid;
        int c = j >> 6, kw = j & 63;
        lw[(c << 6) | (((kw >> 2) ^ (c & 7)) << 2) | (kw & 3)] = Wt[j];
    }
    __syncthreads();
    const int wave = tid >> 6, l = tid & 63;
    const int hl = l >> 4;
    const int arow = (wave << 4) | (l & 15);
    f32x4 acc[8];
#pragma unroll
    for (int f = 0; f < 8; ++f) acc[f] = (f32x4){0.f, 0.f, 0.f, 0.f};
#pragma unroll
    for (int ks = 0; ks < 4; ++ks) {
        int ua = (ks << 2) + hl;  // 16B-unit index along K
        bf16x8 af = *(const bf16x8*)&lx[(arow << 6) | ((ua ^ (arow & 7)) << 2)];
#pragma unroll
        for (int f = 0; f < 8; ++f) {
            int bcol = (f << 4) | (l & 15);
            bf16x8 bf = *(const bf16x8*)&lw[(bcol << 6) | ((ua ^ (bcol & 7)) << 2)];
            acc[f] = __builtin_amdgcn_mfma_f32_16x16x32_bf16(af, bf, acc[f], 0, 0, 0);
        }
    }
    // epilogue: D col = lane&15, row = (lane>>4)*4 + reg
    const int rbase = brow + (wave << 4) + (hl << 2);
    float dv[4];
#pragma unroll
    for (int r = 0; r < 4; ++r) dv[r] = (rbase + r < M) ? dinv[rbase + r] : 0.f;
#pragma unroll
    for (int f = 0; f < 8; ++f) {
#pragma unroll
        for (int r = 0; r < 4; ++r) {
            float mine = acc[f][r] * dv[r];
            float other = __shfl_xor(mine, 1, 64);
            if (!(l & 1)) {
                int row = rbase + r;
                if (row < M)
                    Hs[(size_t)row * 64 + ((f << 3) | ((l & 15) >> 1))] = packbf2(mine, other);
            }
        }
    }
}

// ---------- gather body ----------
__device__ inline void gather_row(const uint* __restrict__ Hs, const int* __restrict__ csr,
                                  int e, int end, int t, float& ax, float& ay) {
    for (; e + 16 <= end; e += 16) {
        uint uu[16];
#pragma unroll
        for (int k = 0; k < 16; ++k) uu[k] = Hs[(size_t)csr[e + k] * 64 + t];
#pragma unroll
        for (int k = 0; k < 16; ++k) { ax += bflo(uu[k]); ay += bfhi(uu[k]); }
    }
    for (; e + 4 <= end; e += 4) {
        uint uu[4];
#pragma unroll
        for (int k = 0; k < 4; ++k) uu[k] = Hs[(size_t)csr[e + k] * 64 + t];
#pragma unroll
        for (int k = 0; k < 4; ++k) { ax += bflo(uu[k]); ay += bfhi(uu[k]); }
    }
    for (; e < end; ++e) {
        uint uu = Hs[(size_t)csr[e] * 64 + t];
        ax += bflo(uu); ay += bfhi(uu);
    }
}

// ---------- gather layer 1 ----------
__global__ __launch_bounds__(256) void gather1_kernel(const uint* __restrict__ Hs,
        const int* __restrict__ rowptr, const int* __restrict__ csr,
        const float* __restrict__ dinv, const float* __restrict__ b1,
        uint* __restrict__ A, int n) {
    int i = blockIdx.x * 4 + (threadIdx.x >> 6);
    int t = threadIdx.x & 63;
    if (i >= n) return;
    uint u = Hs[(size_t)i * 64 + t];  // self-loop
    float ax = bflo(u), ay = bfhi(u);
    gather_row(Hs, csr, rowptr[i], rowptr[i + 1], t, ax, ay);
    float di = dinv[i];
    float2 b = *(const float2*)(b1 + 2 * t);
    A[(size_t)i * 64 + t] = packbf2(fmaxf(di * ax + b.x, 0.0f),
                                    fmaxf(di * ay + b.y, 0.0f));
}

// ---------- gather layer 2 + pooled-merge atomics ----------
__global__ __launch_bounds__(512) void gather2_kernel(const uint* __restrict__ Hs,
        const int* __restrict__ rowptr, const int* __restrict__ csr,
        const float* __restrict__ dinv, const int* __restrict__ batch,
        float* __restrict__ out, int n) {
    __shared__ float sh[8][DIM];
    __shared__ int sgid[8];
    int w = threadIdx.x >> 6;
    int t = threadIdx.x & 63;
    int i = blockIdx.x * 8 + w;
    if (i < n) {
        uint u = Hs[(size_t)i * 64 + t];
        float ax = bflo(u), ay = bfhi(u);
        gather_row(Hs, csr, rowptr[i], rowptr[i + 1], t, ax, ay);
        float di = dinv[i];
        sh[w][2 * t]     = di * ax;
        sh[w][2 * t + 1] = di * ay;
        if (t == 0) sgid[w] = batch[i];
    } else if (t == 0) {
        sgid[w] = -1;
    }
    __syncthreads();
    if (threadIdx.x < DIM) {
        int d = threadIdx.x;
        int curg = -1; float run = 0.0f;
#pragma unroll
        for (int r = 0; r < 8; ++r) {
            int g = sgid[r];
            if (g < 0) continue;
            if (g != curg) {
                if (curg >= 0) atomicAdd(&out[(size_t)curg * DIM + d], run);
                curg = g; run = sh[r][d];
            } else {
                run += sh[r][d];
            }
        }
        if (curg >= 0) atomicAdd(&out[(size_t)curg * DIM + d], run);
    }
}

// ---------- finalize ----------
__global__ void fin_kernel(float* __restrict__ out, const int* __restrict__ cnt,
                           const float* __restrict__ b2, int nG) {
    int tid = blockIdx.x * blockDim.x + threadIdx.x;
    int g = tid >> 7;
    int d = tid & (DIM - 1);
    if (g >= nG) return;
    float c = (float)cnt[g];
    out[tid] = (out[tid] + c * b2[d]) / fmaxf(c, 1.0f);
}

extern "C" void kernel_launch(void* const* d_in, const int* in_sizes, int n_in,
                              void* d_out, int out_size, void* d_ws, size_t ws_size,
                              hipStream_t stream) {
    const float* x     = (const float*)d_in[0];
    const int*   ei    = (const int*)d_in[1];
    const int*   batch = (const int*)d_in[2];
    const float* W1    = (const float*)d_in[3];
    const float* b1    = (const float*)d_in[4];
    const float* W2    = (const float*)d_in[5];
    const float* b2    = (const float*)d_in[6];
    float* out = (float*)d_out;

    const int n  = in_sizes[0] / DIM;   // 50000
    const int nE = in_sizes[1] / 2;     // 800000
    const int nG = out_size / DIM;      // 512

    const int* src = ei;
    const int* dst = ei + nE;

    const int nw  = (n + 1) >> 1;
    const int WPC = (nw + 3) & ~3;
    const size_t packBytes = (size_t)n * 64 * sizeof(uint);          // 12.8 MB
    const size_t partBytes = (size_t)NCH * WPC * 4;                  // 25.6 MB
    const size_t ldsBytes  = (size_t)WPC * 4;                        // ~100 KB

    char* ws = (char*)d_ws;
    size_t off = 0;
    auto alloc = [&](size_t bytes) { void* p = ws + off; off = (off + bytes + 255) & ~(size_t)255; return p; };
    // part (CSR phase) aliases Hs+A (layer phase): part dead before gemm1 writes Hs.
    size_t bigBytes = partBytes > 2 * packBytes ? partBytes : 2 * packBytes;
    char*  big    = (char*)alloc(bigBytes);
    uint*  part   = (uint*)big;
    uint*  Hs     = (uint*)big;
    uint*  A      = (uint*)(big + packBytes);
    uint*  xb     = (uint*)alloc(packBytes);
    int*   deg    = (int*)alloc((size_t)n * 4);
    int*   cnt    = (int*)alloc((size_t)nG * 4);
    float* dinv   = (float*)alloc((size_t)n * 4);
    int*   rowptr = (int*)alloc((size_t)(n + 1) * 4);
    int*   bsum   = (int*)alloc(256);
    uint*  Wt1    = (uint*)alloc(8192 * 4);
    uint*  Wt2    = (uint*)alloc(8192 * 4);
    int*   csr    = (int*)alloc((size_t)nE * 4);

    const int B = 256;
    const int nb = (n + 1023) / 1024;  // 49 (<= 64)

    hipMemsetAsync(cnt, 0, (size_t)nG * 4, stream);
    hipMemsetAsync(out, 0, (size_t)out_size * sizeof(float), stream);

    cvtx_kernel<<<(n * 64 + B - 1) / B, B, 0, stream>>>(x, xb, n * 64);
    cvtw_kernel<<<32, 256, 0, stream>>>(W1, Wt1);
    cvtw_kernel<<<32, 256, 0, stream>>>(W2, Wt2);
    cnt_kernel<<<64, 256, 0, stream>>>(batch, cnt, n, nG);
    hist_kernel<<<NCH, 256, ldsBytes, stream>>>(dst, part, nE, n, WPC);
    reduce_kernel<<<(nw + B - 1) / B, B, 0, stream>>>(part, deg, n, WPC);
    scan1_kernel<<<nb, 1024, 0, stream>>>(deg, bsum, n);
    scan2_kernel<<<1, 64, 0, stream>>>(bsum, rowptr, nb, n);
    scan3_kernel<<<nb, 1024, 0, stream>>>(deg, bsum, rowptr, dinv, n);
    fill_kernel<<<NCH, 256, ldsBytes, stream>>>(src, dst, part, rowptr, csr, nE, n, WPC);

    // Layer 1
    gemm_mfma_kernel<<<(n + 63) / 64, 256, 0, stream>>>(xb, Wt1, dinv, Hs, n);
    gather1_kernel<<<(n + 3) / 4, 256, 0, stream>>>(Hs, rowptr, csr, dinv, b1, A, n);

    // Layer 2
    gemm_mfma_kernel<<<(n + 63) / 64, 256, 0, stream>>>(A, Wt2, dinv, Hs, n);
    gather2_kernel<<<(n + 7) / 8, 512, 0, stream>>>(Hs, rowptr, csr, dinv, batch, out, n);

    fin_kernel<<<(nG * DIM + B - 1) / B, B, 0, stream>>>(out, cnt, b2, nG);
}